// Round 1
// baseline (1696.059 us; speedup 1.0000x reference)
//
#include <hip/hip_runtime.h>

// ResidualVQ: B=8, T=2048, D=256, Q=8, K=1024
// N = B*T = 16384 rows.
// d_out layout (float): [0, N*D) quantized_out
//                       [N*D, N*D + Q*N) indices (as float values)
//                       [N*D + Q*N, +Q) losses
// d_ws layout (float):  [0, N*D) residual buffer
//                       [N*D, N*D + Q*K) codebook squared norms

constexpr int Dd = 256;
constexpr int Kk = 1024;
constexpr int Qq = 8;
constexpr int Nn = 16384;
constexpr int MR = 32;   // rows per block
constexpr int KT = 64;   // codes per k-tile
constexpr int DC = 64;   // dims per chunk

// One block = 256 threads computes squared norms for 16 codebook rows.
__global__ __launch_bounds__(256) void norms_kernel(const float* __restrict__ cb,
                                                    float* __restrict__ norms) {
    int code = blockIdx.x * 16 + (threadIdx.x >> 4);
    int j = threadIdx.x & 15;
    const float4* row = (const float4*)(cb + (size_t)code * Dd);
    float s = 0.f;
#pragma unroll
    for (int i = 0; i < 4; ++i) {
        float4 v = row[j * 4 + i];
        s = fmaf(v.x, v.x, s);
        s = fmaf(v.y, v.y, s);
        s = fmaf(v.z, v.z, s);
        s = fmaf(v.w, v.w, s);
    }
#pragma unroll
    for (int off = 8; off >= 1; off >>= 1) s += __shfl_down(s, off, 16);
    if (j == 0) norms[code] = s;
}

__global__ __launch_bounds__(256) void vq_layer(
    const float* __restrict__ src,      // x (layer 0) or residual
    float* __restrict__ residual,       // ws, written in place
    const float* __restrict__ cb,       // this layer's codebook [K][D]
    const float* __restrict__ norms,    // this layer's [K]
    float* __restrict__ qsum,           // d_out quantized sum
    float* __restrict__ idx_out,        // this layer's [N] (float)
    float* __restrict__ loss_out,       // this layer's scalar
    int first)
{
    __shared__ float res[MR][Dd];       // 32 KB
    __shared__ float cbt[DC][KT];       // 16 KB, transposed [d][k]
    __shared__ int bestIdxS[MR];
    __shared__ float wloss[4];

    const int tid = threadIdx.x;
    const int tx = tid & 31;            // code lane: codes 2*tx, 2*tx+1
    const int ty = tid >> 5;            // row group 0..7 (rows ty*4 .. ty*4+3)
    const int rowbase = blockIdx.x * MR;

    // Stage this block's 32 residual rows into LDS (coalesced float4).
    {
        const float4* g = (const float4*)(src + (size_t)rowbase * Dd);
        float4* s = (float4*)&res[0][0];
#pragma unroll
        for (int i = 0; i < 8; ++i) s[tid + i * 256] = g[tid + i * 256];
    }

    float best[4];
    int bidx[4];
#pragma unroll
    for (int r = 0; r < 4; ++r) { best[r] = -3.4e38f; bidx[r] = 0; }

    for (int kt = 0; kt < Kk; kt += KT) {
        float acc[4][2] = {};
        for (int dc = 0; dc < Dd; dc += DC) {
            __syncthreads();   // protect cbt from previous tile's readers
            // Stage 64 codes x 64 dims, transposed into cbt[d][k].
            {
                int c = tid >> 2;   // 0..63 code within tile
                int p = tid & 3;    // 0..3 sixteen-dim part
                const float4* g = (const float4*)(cb + (size_t)(kt + c) * Dd + dc + p * 16);
#pragma unroll
                for (int i = 0; i < 4; ++i) {
                    float4 v = g[i];
                    int d0 = p * 16 + i * 4;
                    cbt[d0 + 0][c] = v.x;
                    cbt[d0 + 1][c] = v.y;
                    cbt[d0 + 2][c] = v.z;
                    cbt[d0 + 3][c] = v.w;
                }
            }
            __syncthreads();
            // Accumulate 4 rows x 2 codes over this 64-dim chunk.
#pragma unroll
            for (int d = 0; d < DC; d += 4) {
                float4 rv[4];
#pragma unroll
                for (int r = 0; r < 4; ++r)
                    rv[r] = *(const float4*)&res[ty * 4 + r][dc + d];
#pragma unroll
                for (int j = 0; j < 4; ++j) {
                    float c0 = cbt[d + j][tx * 2 + 0];
                    float c1 = cbt[d + j][tx * 2 + 1];
#pragma unroll
                    for (int r = 0; r < 4; ++r) {
                        float x = (&rv[r].x)[j];
                        acc[r][0] = fmaf(x, c0, acc[r][0]);
                        acc[r][1] = fmaf(x, c1, acc[r][1]);
                    }
                }
            }
        }
        // Score this k-tile and update running argmax (prefer smaller index on tie).
#pragma unroll
        for (int j = 0; j < 2; ++j) {
            int k = kt + tx * 2 + j;
            float nrm = norms[k];
#pragma unroll
            for (int r = 0; r < 4; ++r) {
                float sc = fmaf(2.0f, acc[r][j], -nrm);
                if (sc > best[r] || (sc == best[r] && k < bidx[r])) {
                    best[r] = sc; bidx[r] = k;
                }
            }
        }
    }

    // Reduce argmax across the 32 code-lanes (same ty stays within a 32-lane half).
#pragma unroll
    for (int off = 16; off >= 1; off >>= 1) {
#pragma unroll
        for (int r = 0; r < 4; ++r) {
            float ob = __shfl_xor(best[r], off);
            int   oi = __shfl_xor(bidx[r], off);
            if (ob > best[r] || (ob == best[r] && oi < bidx[r])) {
                best[r] = ob; bidx[r] = oi;
            }
        }
    }
    if (tx == 0) {
#pragma unroll
        for (int r = 0; r < 4; ++r) bestIdxS[ty * 4 + r] = bidx[r];
    }
    __syncthreads();

    // Gather + residual update + qsum accumulate + loss partial.
    float lpart = 0.f;
    {
        int row = tid >> 3;   // 0..31
        int seg = tid & 7;    // 0..7
        int k = bestIdxS[row];
        int grow = rowbase + row;
#pragma unroll
        for (int i = 0; i < 8; ++i) {
            int d = seg * 4 + i * 32;
            float4 e = *(const float4*)(cb + (size_t)k * Dd + d);
            float4 r = *(const float4*)&res[row][d];
            float4 rn;
            rn.x = r.x - e.x; rn.y = r.y - e.y; rn.z = r.z - e.z; rn.w = r.w - e.w;
            *(float4*)(residual + (size_t)grow * Dd + d) = rn;
            float4* qp = (float4*)(qsum + (size_t)grow * Dd + d);
            if (first) {
                *qp = e;
            } else {
                float4 o = *qp;
                o.x += e.x; o.y += e.y; o.z += e.z; o.w += e.w;
                *qp = o;
            }
            lpart = fmaf(rn.x, rn.x, lpart);
            lpart = fmaf(rn.y, rn.y, lpart);
            lpart = fmaf(rn.z, rn.z, lpart);
            lpart = fmaf(rn.w, rn.w, lpart);
        }
    }

    if (tid < MR) idx_out[rowbase + tid] = (float)bestIdxS[tid];

    // Block loss reduction -> one atomic per block.
#pragma unroll
    for (int off = 32; off >= 1; off >>= 1) lpart += __shfl_down(lpart, off);
    if ((tid & 63) == 0) wloss[tid >> 6] = lpart;
    __syncthreads();
    if (tid == 0) {
        float s = wloss[0] + wloss[1] + wloss[2] + wloss[3];
        atomicAdd(loss_out, s * (1.0f / ((float)Nn * (float)Dd)));
    }
}

extern "C" void kernel_launch(void* const* d_in, const int* in_sizes, int n_in,
                              void* d_out, int out_size, void* d_ws, size_t ws_size,
                              hipStream_t stream) {
    const float* x   = (const float*)d_in[0];   // [B,T,D] = [N,D]
    const float* cbs = (const float*)d_in[1];   // [Q,K,D]
    float* out    = (float*)d_out;
    float* qsum   = out;                         // [N*D]
    float* idxs   = out + (size_t)Nn * Dd;       // [Q*N]
    float* losses = idxs + (size_t)Qq * Nn;      // [Q]
    float* residual = (float*)d_ws;              // [N*D]
    float* norms    = residual + (size_t)Nn * Dd; // [Q*K]

    hipMemsetAsync(losses, 0, Qq * sizeof(float), stream);
    norms_kernel<<<(Qq * Kk) / 16, 256, 0, stream>>>(cbs, norms);

    for (int q = 0; q < Qq; ++q) {
        vq_layer<<<Nn / MR, 256, 0, stream>>>(
            q == 0 ? x : residual, residual,
            cbs + (size_t)q * Kk * Dd, norms + (size_t)q * Kk,
            qsum, idxs + (size_t)q * Nn, losses + q, q == 0 ? 1 : 0);
    }
}

// Round 2
// 1180.456 us; speedup vs baseline: 1.4368x; 1.4368x over previous
//
#include <hip/hip_runtime.h>

// ResidualVQ: B=8, T=2048, D=256, Q=8, K=1024. N = B*T = 16384 rows.
// d_out (float): [0, N*D) quantized_out  (used as the residual buffer during
//                                         the layer loop; finalized to x - r)
//                [N*D, N*D + Q*N) indices (as float)
//                [N*D + Q*N, +Q) losses
// d_ws (float):  [0, Q*D*K) transposed codebooks cbT[q][d][k]  (8 MB)
//                [Q*D*K, +Q*K) codebook squared norms

constexpr int Dd = 256;
constexpr int Kk = 1024;
constexpr int Qq = 8;
constexpr int Nn = 16384;
constexpr int MR = 16;   // rows per block

// ---- squared norms: one block computes 16 codebook rows ----
__global__ __launch_bounds__(256) void norms_kernel(const float* __restrict__ cb,
                                                    float* __restrict__ norms) {
    int code = blockIdx.x * 16 + (threadIdx.x >> 4);
    int j = threadIdx.x & 15;
    const float4* row = (const float4*)(cb + (size_t)code * Dd);
    float s = 0.f;
#pragma unroll
    for (int i = 0; i < 4; ++i) {
        float4 v = row[j * 4 + i];
        s = fmaf(v.x, v.x, s);
        s = fmaf(v.y, v.y, s);
        s = fmaf(v.z, v.z, s);
        s = fmaf(v.w, v.w, s);
    }
#pragma unroll
    for (int off = 8; off >= 1; off >>= 1) s += __shfl_down(s, off, 16);
    if (j == 0) norms[code] = s;
}

// ---- transpose all codebooks: cbT[q][d][k] = cb[q][k][d] ----
// grid = Q * (K/64) * (D/64) = 512 blocks
__global__ __launch_bounds__(256) void transpose_kernel(const float* __restrict__ cb,
                                                        float* __restrict__ cbT) {
    int b = blockIdx.x;
    int q  = b >> 6;
    int kt = ((b >> 2) & 15) * 64;
    int dt = (b & 3) * 64;
    __shared__ float tile[64][68];
    int tid = threadIdx.x;
    int r = tid >> 2;          // 0..63
    int p = tid & 3;           // 0..3
    const float* src = cb + ((size_t)q * Kk + kt + r) * Dd + dt + p * 16;
#pragma unroll
    for (int j = 0; j < 4; ++j)
        *(float4*)&tile[r][p * 16 + j * 4] = *(const float4*)(src + j * 4);
    __syncthreads();
    float* dst = cbT + ((size_t)q * Dd + dt + r) * Kk + kt + p * 16;
#pragma unroll
    for (int j = 0; j < 4; ++j) {
        float4 v;
        v.x = tile[p * 16 + j * 4 + 0][r];
        v.y = tile[p * 16 + j * 4 + 1][r];
        v.z = tile[p * 16 + j * 4 + 2][r];
        v.w = tile[p * 16 + j * 4 + 3][r];
        *(float4*)(dst + j * 4) = v;
    }
}

// ---- one VQ layer ----
// Wave w handles ALL 16 rows x its 256-code slice [w*256, w*256+256).
// Lane l owns 4 codes: k = w*256 + l*4 .. +3.  acc[16][4] in registers.
__global__ __launch_bounds__(256, 4) void vq_layer(
    const float* __restrict__ src,      // x (layer 0) or residual (in d_out)
    float* __restrict__ resid,          // residual out (d_out region)
    const float* __restrict__ cb,       // this layer's codebook [K][D]
    const float* __restrict__ cbT,      // this layer's transposed [D][K]
    const float* __restrict__ norms,    // this layer's [K]
    float* __restrict__ idx_out,        // this layer's [N] (float)
    float* __restrict__ loss_out)       // this layer's scalar
{
    __shared__ float res[MR][Dd];       // 16 KB
    __shared__ float wbest[4][MR];
    __shared__ int   widx[4][MR];
    __shared__ int   bestIdxS[MR];
    __shared__ float wloss[4];

    const int tid = threadIdx.x;
    const int w = tid >> 6;             // wave 0..3
    const int l = tid & 63;             // lane 0..63
    const int rowbase = blockIdx.x * MR;

    // Stage the block's 16 rows (coalesced float4).
    {
        const float4* g = (const float4*)(src + (size_t)rowbase * Dd);
        float4* s = (float4*)&res[0][0];
#pragma unroll
        for (int i = 0; i < 4; ++i) s[tid + i * 256] = g[tid + i * 256];
    }
    __syncthreads();

    const int kbase = w * 256 + l * 4;          // this lane's first code
    const float4* eT = (const float4*)cbT;      // [D][K/4]
    const int kq = kbase >> 2;

    float acc[MR][4] = {};

#pragma unroll 2
    for (int d = 0; d < Dd; d += 4) {
        float4 e0 = eT[(size_t)(d + 0) * (Kk / 4) + kq];
        float4 e1 = eT[(size_t)(d + 1) * (Kk / 4) + kq];
        float4 e2 = eT[(size_t)(d + 2) * (Kk / 4) + kq];
        float4 e3 = eT[(size_t)(d + 3) * (Kk / 4) + kq];
#pragma unroll
        for (int r = 0; r < MR; ++r) {
            float4 xv = *(const float4*)&res[r][d];   // broadcast (1 addr/wave)
            acc[r][0] = fmaf(xv.x, e0.x, acc[r][0]);
            acc[r][1] = fmaf(xv.x, e0.y, acc[r][1]);
            acc[r][2] = fmaf(xv.x, e0.z, acc[r][2]);
            acc[r][3] = fmaf(xv.x, e0.w, acc[r][3]);
            acc[r][0] = fmaf(xv.y, e1.x, acc[r][0]);
            acc[r][1] = fmaf(xv.y, e1.y, acc[r][1]);
            acc[r][2] = fmaf(xv.y, e1.z, acc[r][2]);
            acc[r][3] = fmaf(xv.y, e1.w, acc[r][3]);
            acc[r][0] = fmaf(xv.z, e2.x, acc[r][0]);
            acc[r][1] = fmaf(xv.z, e2.y, acc[r][1]);
            acc[r][2] = fmaf(xv.z, e2.z, acc[r][2]);
            acc[r][3] = fmaf(xv.z, e2.w, acc[r][3]);
            acc[r][0] = fmaf(xv.w, e3.x, acc[r][0]);
            acc[r][1] = fmaf(xv.w, e3.y, acc[r][1]);
            acc[r][2] = fmaf(xv.w, e3.z, acc[r][2]);
            acc[r][3] = fmaf(xv.w, e3.w, acc[r][3]);
        }
    }

    // Score and in-lane argmax over this lane's 4 codes (tie -> smaller k).
    float4 nrm = *(const float4*)(norms + kbase);
    float best[MR];
    int bidx[MR];
#pragma unroll
    for (int r = 0; r < MR; ++r) {
        float s0 = fmaf(2.0f, acc[r][0], -nrm.x);
        float s1 = fmaf(2.0f, acc[r][1], -nrm.y);
        float s2 = fmaf(2.0f, acc[r][2], -nrm.z);
        float s3 = fmaf(2.0f, acc[r][3], -nrm.w);
        float b = s0; int bi = kbase;
        if (s1 > b) { b = s1; bi = kbase + 1; }
        if (s2 > b) { b = s2; bi = kbase + 2; }
        if (s3 > b) { b = s3; bi = kbase + 3; }
        best[r] = b; bidx[r] = bi;
    }
    // Cross-lane reduce (64 lanes).
#pragma unroll
    for (int off = 32; off >= 1; off >>= 1) {
#pragma unroll
        for (int r = 0; r < MR; ++r) {
            float ob = __shfl_xor(best[r], off);
            int   oi = __shfl_xor(bidx[r], off);
            if (ob > best[r] || (ob == best[r] && oi < bidx[r])) {
                best[r] = ob; bidx[r] = oi;
            }
        }
    }
    if (l == 0) {
#pragma unroll
        for (int r = 0; r < MR; ++r) { wbest[w][r] = best[r]; widx[w][r] = bidx[r]; }
    }
    __syncthreads();
    // Cross-wave combine (each wave covered a distinct 256-code slice).
    if (tid < MR) {
        float b = wbest[0][tid]; int bi = widx[0][tid];
#pragma unroll
        for (int ww = 1; ww < 4; ++ww) {
            float ob = wbest[ww][tid]; int oi = widx[ww][tid];
            if (ob > b || (ob == b && oi < bi)) { b = ob; bi = oi; }
        }
        bestIdxS[tid] = bi;
        idx_out[rowbase + tid] = (float)bi;
    }
    __syncthreads();

    // Gather + residual write + loss partial. 16 threads per row.
    float lpart = 0.f;
    {
        int row = tid >> 4;     // 0..15
        int seg = tid & 15;     // 0..15
        int k = bestIdxS[row];
        int grow = rowbase + row;
#pragma unroll
        for (int i = 0; i < 4; ++i) {
            int d = seg * 4 + i * 64;
            float4 e = *(const float4*)(cb + (size_t)k * Dd + d);
            float4 r = *(const float4*)&res[row][d];
            float4 rn;
            rn.x = r.x - e.x; rn.y = r.y - e.y; rn.z = r.z - e.z; rn.w = r.w - e.w;
            *(float4*)(resid + (size_t)grow * Dd + d) = rn;
            lpart = fmaf(rn.x, rn.x, lpart);
            lpart = fmaf(rn.y, rn.y, lpart);
            lpart = fmaf(rn.z, rn.z, lpart);
            lpart = fmaf(rn.w, rn.w, lpart);
        }
    }
#pragma unroll
    for (int off = 32; off >= 1; off >>= 1) lpart += __shfl_down(lpart, off);
    if ((tid & 63) == 0) wloss[tid >> 6] = lpart;
    __syncthreads();
    if (tid == 0) {
        float s = wloss[0] + wloss[1] + wloss[2] + wloss[3];
        atomicAdd(loss_out, s * (1.0f / ((float)Nn * (float)Dd)));
    }
}

// ---- finalize: quantized_out = x - final_residual (in place in d_out) ----
__global__ __launch_bounds__(256) void finalize_kernel(const float* __restrict__ x,
                                                       float* __restrict__ out) {
    const float4* xg = (const float4*)x;
    float4* og = (float4*)out;
    size_t n4 = (size_t)Nn * Dd / 4;
    for (size_t i = (size_t)blockIdx.x * 256 + threadIdx.x; i < n4;
         i += (size_t)gridDim.x * 256) {
        float4 a = xg[i], b = og[i];
        float4 o;
        o.x = a.x - b.x; o.y = a.y - b.y; o.z = a.z - b.z; o.w = a.w - b.w;
        og[i] = o;
    }
}

extern "C" void kernel_launch(void* const* d_in, const int* in_sizes, int n_in,
                              void* d_out, int out_size, void* d_ws, size_t ws_size,
                              hipStream_t stream) {
    const float* x   = (const float*)d_in[0];   // [N,D]
    const float* cbs = (const float*)d_in[1];   // [Q,K,D]
    float* out    = (float*)d_out;
    float* resid  = out;                          // residual lives here
    float* idxs   = out + (size_t)Nn * Dd;        // [Q*N]
    float* losses = idxs + (size_t)Qq * Nn;       // [Q]
    float* cbT    = (float*)d_ws;                 // [Q][D][K]
    float* norms  = cbT + (size_t)Qq * Dd * Kk;   // [Q*K]

    hipMemsetAsync(losses, 0, Qq * sizeof(float), stream);
    norms_kernel<<<(Qq * Kk) / 16, 256, 0, stream>>>(cbs, norms);
    transpose_kernel<<<Qq * (Kk / 64) * (Dd / 64), 256, 0, stream>>>(cbs, cbT);

    for (int q = 0; q < Qq; ++q) {
        vq_layer<<<Nn / MR, 256, 0, stream>>>(
            q == 0 ? x : resid, resid,
            cbs + (size_t)q * Kk * Dd,
            cbT + (size_t)q * Dd * Kk,
            norms + (size_t)q * Kk,
            idxs + (size_t)q * Nn, losses + q);
    }
    finalize_kernel<<<1024, 256, 0, stream>>>(x, out);
}

// Round 4
// 605.632 us; speedup vs baseline: 2.8005x; 1.9491x over previous
//
#include <hip/hip_runtime.h>

// ResidualVQ: B=8, T=2048, D=256, Q=8, K=1024. N = B*T = 16384.
// Scoring via fp16 split-MFMA: 2x = xh + xl, e = eh + el (fp16 RTNE).
// 2x.e ~= xh.eh + xh.el + xl.eh  (dropped xl.el ~ 2e-6, below fp32 noise).
// One GEMM, reduce length 768, mapped into 512-wide packed buffers:
//   d' in [0,256):   A: eh  (ecat col d')      B: xh (xcat col d')
//   d' in [256,512): A: el  (ecat col d')      B: xh (xcat col d'-256)
//   d' in [512,768): A: eh  (ecat col d'-512)  B: xl (xcat col d'-256)
// score = acc - |e|^2  (row-constant |x|^2 dropped; same argmax).
//
// d_out (float): [0, N*D) quantized_out (residual during loop; finalized x-r)
//                [N*D, +Q*N) indices (as float)   [then +Q) losses
// d_ws: xcat f16[N][512] | ecat f16[Q*K][512] | norms f32[Q*K] | partial float2[4][N]

typedef _Float16 f16;
typedef f16 f16x8 __attribute__((ext_vector_type(8)));
typedef float f32x4 __attribute__((ext_vector_type(4)));

constexpr int Dd = 256;
constexpr int Kk = 1024;
constexpr int Qq = 8;
constexpr int Nn = 16384;

__device__ inline void gload16(const f16* g, f16* l) {
    __builtin_amdgcn_global_load_lds(
        (const __attribute__((address_space(1))) unsigned int*)(const __attribute__((address_space(1))) f16*)g,
        (__attribute__((address_space(3))) unsigned int*)(__attribute__((address_space(3))) f16*)l,
        16, 0, 0);
}

// ---- squared norms: one block computes 16 codebook rows ----
__global__ __launch_bounds__(256) void norms_kernel(const float* __restrict__ cb,
                                                    float* __restrict__ norms) {
    int code = blockIdx.x * 16 + (threadIdx.x >> 4);
    int j = threadIdx.x & 15;
    const float4* row = (const float4*)(cb + (size_t)code * Dd);
    float s = 0.f;
#pragma unroll
    for (int i = 0; i < 4; ++i) {
        float4 v = row[j * 4 + i];
        s = fmaf(v.x, v.x, s); s = fmaf(v.y, v.y, s);
        s = fmaf(v.z, v.z, s); s = fmaf(v.w, v.w, s);
    }
#pragma unroll
    for (int off = 8; off >= 1; off >>= 1) s += __shfl_down(s, off, 16);
    if (j == 0) norms[code] = s;
}

// ---- build ecat[Q*K][512] = [eh|el] from fp32 codebooks ----
__global__ __launch_bounds__(256) void build_ecat(const float* __restrict__ cb,
                                                  f16* __restrict__ ecat) {
    int row = blockIdx.x * 8 + (threadIdx.x >> 5);
    int p = threadIdx.x & 31;
    const float* s = cb + (size_t)row * Dd + p * 8;
    f16x8 hi, lo;
#pragma unroll
    for (int j = 0; j < 8; ++j) {
        float v = s[j];
        f16 h = (f16)v;
        hi[j] = h; lo[j] = (f16)(v - (float)h);
    }
    *(f16x8*)(ecat + (size_t)row * 512 + p * 8) = hi;
    *(f16x8*)(ecat + (size_t)row * 512 + 256 + p * 8) = lo;
}

// ---- build xcat[N][512] = [xh|xl] of 2*x (layer 0) ----
__global__ __launch_bounds__(256) void build_xcat(const float* __restrict__ src,
                                                  f16* __restrict__ xcat) {
    int row = blockIdx.x * 8 + (threadIdx.x >> 5);
    int p = threadIdx.x & 31;
    const float* s = src + (size_t)row * Dd + p * 8;
    f16x8 hi, lo;
#pragma unroll
    for (int j = 0; j < 8; ++j) {
        float v = 2.f * s[j];
        f16 h = (f16)v;
        hi[j] = h; lo[j] = (f16)(v - (float)h);
    }
    *(f16x8*)(xcat + (size_t)row * 512 + p * 8) = hi;
    *(f16x8*)(xcat + (size_t)row * 512 + 256 + p * 8) = lo;
}

// ---- scoring: block = 128 tokens x 256-code quarter, top-1 per token ----
__global__ __launch_bounds__(256, 2) void score_kernel(
    const f16* __restrict__ xcat,     // [N][512]
    const f16* __restrict__ ecat,     // this layer [K][512]
    const float* __restrict__ norms,  // this layer [K]
    float2* __restrict__ partial)     // [4][N] (val, idx-as-float)
{
    __shared__ f16 tA[2][128 * 32];
    __shared__ f16 tB[2][128 * 32];
    __shared__ float smn[256];
    __shared__ float2 smg[2][128];

    const int tid = threadIdx.x;
    const int w = tid >> 6, l = tid & 63;
    const int wr = w >> 1, wc = w & 1;
    const int l16 = l & 15, h8 = (l >> 4) * 8;

    // XCD-locality swizzle: quarter fixed per XCD pair (grid 512, 8 XCDs)
    const int b = blockIdx.x;
    const int quarter = (b >> 1) & 3;
    const int tokt = (b >> 3) * 2 + (b & 1);
    const int tbase = tokt * 128;
    const int qcb = quarter * 256;

    const int srow = tid >> 2, scol = (tid & 3) * 8;
    const f16* gb = xcat + (size_t)(tbase + srow) * 512 + scol;

    smn[tid] = norms[qcb + tid];

    float bv[4]; int bi[4];
#pragma unroll
    for (int n = 0; n < 4; ++n) { bv[n] = -3.4e38f; bi[n] = 0; }

    int offA[4], offB[4];
#pragma unroll
    for (int m = 0; m < 4; ++m) offA[m] = (wr * 64 + m * 16 + l16) * 32 + h8;
#pragma unroll
    for (int n = 0; n < 4; ++n) offB[n] = (wc * 64 + n * 16 + l16) * 32 + h8;

    for (int chunk = 0; chunk < 2; ++chunk) {
        const int cbase = qcb + chunk * 128;
        const f16* ga = ecat + (size_t)(cbase + srow) * 512 + scol;

        // prologue: stage K-step 0 into buf 0
        gload16(ga,            &tA[0][tid * 8]);
        gload16(ga + 64 * 512, &tA[0][2048 + tid * 8]);
        gload16(gb,            &tB[0][tid * 8]);
        gload16(gb + 64 * 512, &tB[0][2048 + tid * 8]);
        __syncthreads();

        f32x4 acc[4][4];
#pragma unroll
        for (int m = 0; m < 4; ++m)
#pragma unroll
            for (int n = 0; n < 4; ++n) acc[m][n] = (f32x4){0.f, 0.f, 0.f, 0.f};

        int cur = 0;
        for (int s = 0; s < 24; ++s) {
            if (s < 23) {
                int d0 = (s + 1) * 32;
                int aoff = d0 < 512 ? d0 : d0 - 512;       // eh | el | eh
                int boff = d0 < 256 ? d0 : d0 - 256;       // xh | xh | xl
                int nb = cur ^ 1;
                gload16(ga + aoff,            &tA[nb][tid * 8]);
                gload16(ga + aoff + 64 * 512, &tA[nb][2048 + tid * 8]);
                gload16(gb + boff,            &tB[nb][tid * 8]);
                gload16(gb + boff + 64 * 512, &tB[nb][2048 + tid * 8]);
            }
            f16x8 af[4], bf[4];
#pragma unroll
            for (int m = 0; m < 4; ++m) af[m] = *(const f16x8*)&tA[cur][offA[m]];
#pragma unroll
            for (int n = 0; n < 4; ++n) bf[n] = *(const f16x8*)&tB[cur][offB[n]];
#pragma unroll
            for (int m = 0; m < 4; ++m)
#pragma unroll
                for (int n = 0; n < 4; ++n)
                    acc[m][n] = __builtin_amdgcn_mfma_f32_16x16x32_f16(af[m], bf[n], acc[m][n], 0, 0, 0);
            __syncthreads();
            cur ^= 1;
        }

        // epilogue: score = acc - |e|^2 ; running top-1 (ascending code order)
#pragma unroll
        for (int m = 0; m < 4; ++m) {
#pragma unroll
            for (int r = 0; r < 4; ++r) {
                int cl = wr * 64 + m * 16 + (l >> 4) * 4 + r;  // code local in 128-chunk
                float nrm = smn[chunk * 128 + cl];
                int cg = cbase + cl;                           // code id in [0,1024)
#pragma unroll
                for (int n = 0; n < 4; ++n) {
                    float v = acc[m][n][r] - nrm;
                    if (v > bv[n]) { bv[n] = v; bi[n] = cg; }
                }
            }
        }
    }

    // merge across the lane>>4 groups (same token, different codes there)
#pragma unroll
    for (int off = 16; off <= 32; off <<= 1) {
#pragma unroll
        for (int n = 0; n < 4; ++n) {
            float ov = __shfl_xor(bv[n], off);
            int oi = __shfl_xor(bi[n], off);
            if (ov > bv[n] || (ov == bv[n] && oi < bi[n])) { bv[n] = ov; bi[n] = oi; }
        }
    }
    if (l < 16) {
#pragma unroll
        for (int n = 0; n < 4; ++n)
            smg[wr][wc * 64 + n * 16 + l] = make_float2(bv[n], (float)bi[n]);
    }
    __syncthreads();
    if (tid < 128) {
        float2 a = smg[0][tid], c = smg[1][tid];
        float2 r = (c.x > a.x || (c.x == a.x && c.y < a.y)) ? c : a;
        partial[(size_t)quarter * Nn + tbase + tid] = r;
    }
}

// ---- update: merge 4 partials, gather e, residual, loss, idx, next xcat ----
__global__ __launch_bounds__(256) void update_kernel(
    const float* src,                  // x (q=0) or resid
    float* resid,                      // out (d_out region)
    const float* __restrict__ cb,      // layer codebook [K][D]
    const float2* __restrict__ partial,
    f16* __restrict__ xcat,
    float* __restrict__ idx_out,
    float* __restrict__ loss_out,
    int write_xcat)
{
    __shared__ float lsum[8];
    const int tid = threadIdx.x;
    const int row = blockIdx.x * 8 + (tid >> 5);
    const int p = tid & 31;

    float2 bsel = partial[row];
#pragma unroll
    for (int qq = 1; qq < 4; ++qq) {
        float2 c = partial[(size_t)qq * Nn + row];
        if (c.x > bsel.x || (c.x == bsel.x && c.y < bsel.y)) bsel = c;
    }
    const int k = (int)bsel.y;

    const float* e = cb + (size_t)k * Dd + p * 8;
    const float* r = src + (size_t)row * Dd + p * 8;
    float rn[8];
    float lp = 0.f;
#pragma unroll
    for (int j = 0; j < 8; ++j) {
        rn[j] = r[j] - e[j];
        lp = fmaf(rn[j], rn[j], lp);
    }
    float* ro = resid + (size_t)row * Dd + p * 8;
#pragma unroll
    for (int j = 0; j < 8; ++j) ro[j] = rn[j];

    if (write_xcat) {
        f16x8 hi, lo;
#pragma unroll
        for (int j = 0; j < 8; ++j) {
            float v = 2.f * rn[j];
            f16 h = (f16)v;
            hi[j] = h; lo[j] = (f16)(v - (float)h);
        }
        *(f16x8*)(xcat + (size_t)row * 512 + p * 8) = hi;
        *(f16x8*)(xcat + (size_t)row * 512 + 256 + p * 8) = lo;
    }
    if (p == 0) idx_out[row] = (float)k;

#pragma unroll
    for (int off = 16; off >= 1; off >>= 1) lp += __shfl_down(lp, off, 32);
    if (p == 0) lsum[tid >> 5] = lp;
    __syncthreads();
    if (tid == 0) {
        float s = 0.f;
#pragma unroll
        for (int i = 0; i < 8; ++i) s += lsum[i];
        atomicAdd(loss_out, s * (1.0f / ((float)Nn * (float)Dd)));
    }
}

// ---- finalize: quantized_out = x - final_residual (in place in d_out) ----
__global__ __launch_bounds__(256) void finalize_kernel(const float* __restrict__ x,
                                                       float* __restrict__ out) {
    const float4* xg = (const float4*)x;
    float4* og = (float4*)out;
    size_t n4 = (size_t)Nn * Dd / 4;
    for (size_t i = (size_t)blockIdx.x * 256 + threadIdx.x; i < n4;
         i += (size_t)gridDim.x * 256) {
        float4 a = xg[i], b = og[i];
        float4 o;
        o.x = a.x - b.x; o.y = a.y - b.y; o.z = a.z - b.z; o.w = a.w - b.w;
        og[i] = o;
    }
}

extern "C" void kernel_launch(void* const* d_in, const int* in_sizes, int n_in,
                              void* d_out, int out_size, void* d_ws, size_t ws_size,
                              hipStream_t stream) {
    const float* x   = (const float*)d_in[0];   // [N,D]
    const float* cbs = (const float*)d_in[1];   // [Q,K,D]
    float* out    = (float*)d_out;
    float* resid  = out;                          // residual lives in d_out
    float* idxs   = out + (size_t)Nn * Dd;        // [Q*N]
    float* losses = idxs + (size_t)Qq * Nn;       // [Q]

    f16* xcat    = (f16*)d_ws;                          // [N][512]
    f16* ecat    = xcat + (size_t)Nn * 512;             // [Q*K][512]
    float* norms = (float*)(ecat + (size_t)Qq * Kk * 512);  // [Q*K]
    float2* partial = (float2*)(norms + (size_t)Qq * Kk);   // [4][N]

    hipMemsetAsync(losses, 0, Qq * sizeof(float), stream);
    norms_kernel<<<(Qq * Kk) / 16, 256, 0, stream>>>(cbs, norms);
    build_ecat<<<(Qq * Kk) / 8, 256, 0, stream>>>(cbs, ecat);
    build_xcat<<<Nn / 8, 256, 0, stream>>>(x, xcat);

    for (int q = 0; q < Qq; ++q) {
        score_kernel<<<512, 256, 0, stream>>>(
            xcat, ecat + (size_t)q * Kk * 512, norms + (size_t)q * Kk, partial);
        update_kernel<<<Nn / 8, 256, 0, stream>>>(
            q == 0 ? x : resid, resid,
            cbs + (size_t)q * Kk * Dd, partial, xcat,
            idxs + (size_t)q * Nn, losses + q, q < Qq - 1 ? 1 : 0);
    }
    finalize_kernel<<<1024, 256, 0, stream>>>(x, out);
}

// Round 5
// 537.565 us; speedup vs baseline: 3.1551x; 1.1266x over previous
//
#include <hip/hip_runtime.h>

// ResidualVQ: B=8, T=2048, D=256, Q=8, K=1024. N = B*T = 16384.
// Scoring via fp16 split-MFMA: 2x = xh + xl, e = eh + el (fp16 RTNE).
// 2x.e ~= xh.eh + xh.el + xl.eh  (dropped xl.el ~ 2e-6, below fp32 noise).
// One GEMM, reduce length 768, mapped into 512-wide packed buffers:
//   d' in [0,256):   A: eh  (ecat col d')      B: xh (xcat col d')
//   d' in [256,512): A: el  (ecat col d')      B: xh (xcat col d'-256)
//   d' in [512,768): A: eh  (ecat col d'-512)  B: xl (xcat col d'-256)
// score = acc - |e|^2  (row-constant |x|^2 dropped; same argmax).
//
// Residual is carried across layers ONLY as xcat (x = (xh+xl)/2, err ~2^-21);
// fp32 residual is materialized only after the last layer for finalize.
//
// d_out (float): [0, N*D) quantized_out (final residual, then x - r)
//                [N*D, +Q*N) indices (as float)   [then +Q) losses
// d_ws: xcat f16[N][512] | ecat f16[Q*K][512] | norms f32[Q*K] | partial float2[4][N]

typedef _Float16 f16;
typedef f16 f16x8 __attribute__((ext_vector_type(8)));
typedef float f32x4 __attribute__((ext_vector_type(4)));

constexpr int Dd = 256;
constexpr int Kk = 1024;
constexpr int Qq = 8;
constexpr int Nn = 16384;

__device__ inline void gload16(const f16* g, f16* l) {
    __builtin_amdgcn_global_load_lds(
        (const __attribute__((address_space(1))) unsigned int*)(const __attribute__((address_space(1))) f16*)g,
        (__attribute__((address_space(3))) unsigned int*)(__attribute__((address_space(3))) f16*)l,
        16, 0, 0);
}

// ---- build ecat[Q*K][512] = [eh|el] + squared norms, from fp32 codebooks ----
__global__ __launch_bounds__(256) void build_ecat(const float* __restrict__ cb,
                                                  f16* __restrict__ ecat,
                                                  float* __restrict__ norms) {
    int row = blockIdx.x * 8 + (threadIdx.x >> 5);
    int p = threadIdx.x & 31;
    const float* s = cb + (size_t)row * Dd + p * 8;
    f16x8 hi, lo;
    float sq = 0.f;
#pragma unroll
    for (int j = 0; j < 8; ++j) {
        float v = s[j];
        f16 h = (f16)v;
        hi[j] = h; lo[j] = (f16)(v - (float)h);
        sq = fmaf(v, v, sq);
    }
    *(f16x8*)(ecat + (size_t)row * 512 + p * 8) = hi;
    *(f16x8*)(ecat + (size_t)row * 512 + 256 + p * 8) = lo;
#pragma unroll
    for (int off = 16; off >= 1; off >>= 1) sq += __shfl_down(sq, off, 32);
    if (p == 0) norms[row] = sq;
}

// ---- build xcat[N][512] = [xh|xl] of 2*x (layer 0) ----
__global__ __launch_bounds__(256) void build_xcat(const float* __restrict__ src,
                                                  f16* __restrict__ xcat) {
    int row = blockIdx.x * 8 + (threadIdx.x >> 5);
    int p = threadIdx.x & 31;
    const float* s = src + (size_t)row * Dd + p * 8;
    f16x8 hi, lo;
#pragma unroll
    for (int j = 0; j < 8; ++j) {
        float v = 2.f * s[j];
        f16 h = (f16)v;
        hi[j] = h; lo[j] = (f16)(v - (float)h);
    }
    *(f16x8*)(xcat + (size_t)row * 512 + p * 8) = hi;
    *(f16x8*)(xcat + (size_t)row * 512 + 256 + p * 8) = lo;
}

// ---- scoring: block = 256-code slice x 128 tokens, 8 waves, top-1 ----
__global__ __launch_bounds__(512, 4) void score_kernel(
    const f16* __restrict__ xcat,     // [N][512]
    const f16* __restrict__ ecat,     // this layer [K][512]
    const float* __restrict__ norms,  // this layer [K]
    float2* __restrict__ partial)     // [4][N] (val, idx-as-float)
{
    __shared__ f16 tA[2][256 * 32];   // 2 x 16 KB
    __shared__ f16 tB[2][128 * 32];   // 2 x 8 KB
    __shared__ float smn[256];
    __shared__ float2 smg[4][128];

    const int tid = threadIdx.x;
    const int w = tid >> 6, l = tid & 63;
    const int wr = w >> 1, wc = w & 1;          // wr: code quad, wc: token half
    const int l16 = l & 15, hi4 = l >> 4;
    const int h8 = hi4 * 8;

    // XCD-aligned mapping: the 4 slice-blocks of one token tile share
    // (b & 7) -> same XCD, and are 8/16/24 apart in dispatch order.
    const int b = blockIdx.x;
    const int slice = (b >> 3) & 3;             // 256-code slice
    const int tokt = ((b >> 5) << 3) | (b & 7); // 128 token tiles
    const int tbase = tokt * 128;
    const int qcb = slice * 256;

    if (tid < 256) smn[tid] = norms[qcb + tid];

    const int srow = tid >> 2, scol = (tid & 3) * 8;
    const f16* ga = ecat + (size_t)(qcb + srow) * 512 + scol;       // A rows 0..127
    const f16* gb = xcat + (size_t)(tbase + srow) * 512 + scol;     // B rows 0..127

    int offA[4], offB[4];
#pragma unroll
    for (int m = 0; m < 4; ++m) offA[m] = (wr * 64 + m * 16 + l16) * 32 + h8;
#pragma unroll
    for (int n = 0; n < 4; ++n) offB[n] = (wc * 64 + n * 16 + l16) * 32 + h8;

    // prologue: stage K-step 0 into buf 0
    gload16(ga,             &tA[0][tid * 8]);
    gload16(ga + 128 * 512, &tA[0][4096 + tid * 8]);
    gload16(gb,             &tB[0][tid * 8]);
    __syncthreads();

    f32x4 acc[4][4];
#pragma unroll
    for (int m = 0; m < 4; ++m)
#pragma unroll
        for (int n = 0; n < 4; ++n) acc[m][n] = (f32x4){0.f, 0.f, 0.f, 0.f};

    int cur = 0;
    for (int s = 0; s < 24; ++s) {
        if (s < 23) {
            int d0 = (s + 1) * 32;
            int aoff = d0 < 512 ? d0 : d0 - 512;       // eh | el | eh
            int boff = d0 < 256 ? d0 : d0 - 256;       // xh | xh | xl
            int nb = cur ^ 1;
            gload16(ga + aoff,             &tA[nb][tid * 8]);
            gload16(ga + aoff + 128 * 512, &tA[nb][4096 + tid * 8]);
            gload16(gb + boff,             &tB[nb][tid * 8]);
        }
        f16x8 af[4], bf[4];
#pragma unroll
        for (int m = 0; m < 4; ++m) af[m] = *(const f16x8*)&tA[cur][offA[m]];
#pragma unroll
        for (int n = 0; n < 4; ++n) bf[n] = *(const f16x8*)&tB[cur][offB[n]];
#pragma unroll
        for (int m = 0; m < 4; ++m)
#pragma unroll
            for (int n = 0; n < 4; ++n)
                acc[m][n] = __builtin_amdgcn_mfma_f32_16x16x32_f16(af[m], bf[n], acc[m][n], 0, 0, 0);
        __syncthreads();
        cur ^= 1;
    }

    // epilogue: score = acc - |e|^2 ; top-1 (ascending code order)
    float bv[4]; int bi[4];
#pragma unroll
    for (int n = 0; n < 4; ++n) { bv[n] = -3.4e38f; bi[n] = 0; }
#pragma unroll
    for (int m = 0; m < 4; ++m) {
#pragma unroll
        for (int r = 0; r < 4; ++r) {
            int cl = wr * 64 + m * 16 + hi4 * 4 + r;   // code local in 256-slice
            float nrm = smn[cl];
            int cg = qcb + cl;
#pragma unroll
            for (int n = 0; n < 4; ++n) {
                float v = acc[m][n][r] - nrm;
                if (v > bv[n]) { bv[n] = v; bi[n] = cg; }
            }
        }
    }

    // merge across the lane>>4 groups (same token, different codes)
#pragma unroll
    for (int off = 16; off <= 32; off <<= 1) {
#pragma unroll
        for (int n = 0; n < 4; ++n) {
            float ov = __shfl_xor(bv[n], off);
            int oi = __shfl_xor(bi[n], off);
            if (ov > bv[n] || (ov == bv[n] && oi < bi[n])) { bv[n] = ov; bi[n] = oi; }
        }
    }
    if (l < 16) {
#pragma unroll
        for (int n = 0; n < 4; ++n)
            smg[wr][wc * 64 + n * 16 + l] = make_float2(bv[n], (float)bi[n]);
    }
    __syncthreads();
    // merge across the 4 code-quad waves
    if (tid < 128) {
        float2 r = smg[0][tid];
#pragma unroll
        for (int ww = 1; ww < 4; ++ww) {
            float2 c = smg[ww][tid];
            if (c.x > r.x || (c.x == r.x && c.y < r.y)) r = c;
        }
        partial[(size_t)slice * Nn + tbase + tid] = r;
    }
}

// ---- update: merge 4 partials, gather e, next xcat (or final resid), loss, idx ----
__global__ __launch_bounds__(256) void update_kernel(
    const float* __restrict__ x,       // original input (used when q==0)
    float* __restrict__ resid_out,     // d_out region (written when last==1)
    const float* __restrict__ cb,      // layer codebook [K][D] fp32
    const float2* __restrict__ partial,
    f16* __restrict__ xcat,            // read (q>0 src) and written (next layer)
    float* __restrict__ idx_out,
    float* __restrict__ loss_out,
    int q, int last)
{
    __shared__ float lsum[8];
    const int tid = threadIdx.x;
    const int row = blockIdx.x * 8 + (tid >> 5);
    const int p = tid & 31;

    float2 bsel = partial[row];
#pragma unroll
    for (int qq = 1; qq < 4; ++qq) {
        float2 c = partial[(size_t)qq * Nn + row];
        if (c.x > bsel.x || (c.x == bsel.x && c.y < bsel.y)) bsel = c;
    }
    const int k = (int)bsel.y;

    const float* e = cb + (size_t)k * Dd + p * 8;
    float rn[8];
    float lp = 0.f;
    if (q == 0) {
        const float* r = x + (size_t)row * Dd + p * 8;
#pragma unroll
        for (int j = 0; j < 8; ++j) rn[j] = r[j] - e[j];
    } else {
        f16x8 xh = *(const f16x8*)(xcat + (size_t)row * 512 + p * 8);
        f16x8 xl = *(const f16x8*)(xcat + (size_t)row * 512 + 256 + p * 8);
#pragma unroll
        for (int j = 0; j < 8; ++j) {
            float r = ((float)xh[j] + (float)xl[j]) * 0.5f;
            rn[j] = r - e[j];
        }
    }
#pragma unroll
    for (int j = 0; j < 8; ++j) lp = fmaf(rn[j], rn[j], lp);

    if (last) {
        float* ro = resid_out + (size_t)row * Dd + p * 8;
#pragma unroll
        for (int j = 0; j < 8; ++j) ro[j] = rn[j];
    } else {
        f16x8 hi2, lo2;
#pragma unroll
        for (int j = 0; j < 8; ++j) {
            float v = 2.f * rn[j];
            f16 h = (f16)v;
            hi2[j] = h; lo2[j] = (f16)(v - (float)h);
        }
        *(f16x8*)(xcat + (size_t)row * 512 + p * 8) = hi2;
        *(f16x8*)(xcat + (size_t)row * 512 + 256 + p * 8) = lo2;
    }
    if (p == 0) idx_out[row] = (float)k;

#pragma unroll
    for (int off = 16; off >= 1; off >>= 1) lp += __shfl_down(lp, off, 32);
    if (p == 0) lsum[tid >> 5] = lp;
    __syncthreads();
    if (tid == 0) {
        float s = 0.f;
#pragma unroll
        for (int i = 0; i < 8; ++i) s += lsum[i];
        atomicAdd(loss_out, s * (1.0f / ((float)Nn * (float)Dd)));
    }
}

// ---- finalize: quantized_out = x - final_residual (in place in d_out) ----
__global__ __launch_bounds__(256) void finalize_kernel(const float* __restrict__ x,
                                                       float* __restrict__ out) {
    const float4* xg = (const float4*)x;
    float4* og = (float4*)out;
    size_t n4 = (size_t)Nn * Dd / 4;
    for (size_t i = (size_t)blockIdx.x * 256 + threadIdx.x; i < n4;
         i += (size_t)gridDim.x * 256) {
        float4 a = xg[i], b2 = og[i];
        float4 o;
        o.x = a.x - b2.x; o.y = a.y - b2.y; o.z = a.z - b2.z; o.w = a.w - b2.w;
        og[i] = o;
    }
}

extern "C" void kernel_launch(void* const* d_in, const int* in_sizes, int n_in,
                              void* d_out, int out_size, void* d_ws, size_t ws_size,
                              hipStream_t stream) {
    const float* x   = (const float*)d_in[0];   // [N,D]
    const float* cbs = (const float*)d_in[1];   // [Q,K,D]
    float* out    = (float*)d_out;
    float* resid  = out;                          // final residual lives here
    float* idxs   = out + (size_t)Nn * Dd;        // [Q*N]
    float* losses = idxs + (size_t)Qq * Nn;       // [Q]

    f16* xcat    = (f16*)d_ws;                          // [N][512]
    f16* ecat    = xcat + (size_t)Nn * 512;             // [Q*K][512]
    float* norms = (float*)(ecat + (size_t)Qq * Kk * 512);  // [Q*K]
    float2* partial = (float2*)(norms + (size_t)Qq * Kk);   // [4][N]

    hipMemsetAsync(losses, 0, Qq * sizeof(float), stream);
    build_ecat<<<(Qq * Kk) / 8, 256, 0, stream>>>(cbs, ecat, norms);
    build_xcat<<<Nn / 8, 256, 0, stream>>>(x, xcat);

    for (int q = 0; q < Qq; ++q) {
        score_kernel<<<512, 512, 0, stream>>>(
            xcat, ecat + (size_t)q * Kk * 512, norms + (size_t)q * Kk, partial);
        update_kernel<<<Nn / 8, 256, 0, stream>>>(
            x, resid, cbs + (size_t)q * Kk * Dd, partial, xcat,
            idxs + (size_t)q * Nn, losses + q, q, q == Qq - 1 ? 1 : 0);
    }
    finalize_kernel<<<1024, 256, 0, stream>>>(x, out);
}